// Round 1
// baseline (673.941 us; speedup 1.0000x reference)
//
#include <hip/hip_runtime.h>

// DenseEquivariantIrrep: B=32768, C=32, F=32, NS=48, irreps: 4x(d=1), 2x(d=2), 4x(d=3)
// y[b,f,s] = sum_j (sum_{c,r} (x[b,c,:]@fwd)[n,p,r] * (kernel[f,c,:]@fwd)[n,r,q]) * inv[j,s] + bias[f]
//
// Strategy: structured 3-stage contraction fused in one kernel (18.3 GFLOP fp32,
// vector-ALU bound ~116us floor; HBM floor 402MB ~64us). Weights (fwdT, inv, kh)
// precomputed per-launch into d_ws by tiny prep kernels.

#define LD4(arr, base, v) { arr[(base)] = (v).x; arr[(base)+1] = (v).y; arr[(base)+2] = (v).z; arr[(base)+3] = (v).w; }

#define QB4 417   // float4 stride per b-row in LDS (32*13 + 1; 417 mod 8 = 1 -> b-rows hit distinct bank quads)
#define QC4 13    // float4 stride per c-row (13 mod 8 odd -> spreads banks)

// ---- prep 1: fwdT[j][t] and inv[j][t] (= fwd[t][j] * d_j/48) ----
__global__ void prep_ft(const float* __restrict__ d1, const float* __restrict__ d2,
                        const float* __restrict__ d3,
                        float* __restrict__ fwdT, float* __restrict__ invm) {
    int id = blockIdx.x * 256 + threadIdx.x;   // 0..2303
    if (id >= 48 * 48) return;
    int j = id / 48, t = id - j * 48;
    float v, scale;
    if (j < 4) {                       // d=1 irreps: [4][48][1][1]
        v = d1[j * 48 + t];
        scale = 1.0f / 48.0f;
    } else if (j < 12) {               // d=2 irreps: [2][48][2][2]
        int r = j - 4;
        int i = r >> 2, pq = r & 3;
        v = d2[i * 192 + t * 4 + pq];
        scale = 2.0f / 48.0f;
    } else {                           // d=3 irreps: [4][48][3][3]
        int r = j - 12;
        int i = r / 9, pq = r - i * 9;
        v = d3[i * 432 + t * 9 + pq];
        scale = 3.0f / 48.0f;
    }
    fwdT[j * 48 + t] = v;
    invm[j * 48 + t] = v * scale;
}

// ---- prep 2: kh[f][c][j] = sum_t kernel[f][c][t] * fwdT[j][t] ----
__global__ void prep_kh(const float* __restrict__ kern, const float* __restrict__ fwdT,
                        float* __restrict__ kh) {
    int id = blockIdx.x * 256 + threadIdx.x;   // 0..4095
    int f = id >> 7;
    int c = (id >> 2) & 31;
    int jq = id & 3;
    float kr[48];
    const float4* kp = (const float4*)(kern + (f * 32 + c) * 48);
    #pragma unroll
    for (int k = 0; k < 12; ++k) { float4 v = kp[k]; LD4(kr, 4 * k, v); }
    for (int jj = 0; jj < 12; ++jj) {
        int j = jq * 12 + jj;
        const float* fr = fwdT + j * 48;
        float acc = 0.0f;
        #pragma unroll
        for (int t = 0; t < 48; ++t) acc = fmaf(kr[t], fr[t], acc);
        kh[(f * 32 + c) * 48 + j] = acc;
    }
}

// ---- fused main: block = 8 b-rows x 32 f ----
__global__ __launch_bounds__(256, 3) void fused_main(
    const float* __restrict__ x,
    const float* __restrict__ fwdT,
    const float* __restrict__ invm,
    const float* __restrict__ kh,
    const float* __restrict__ bias,
    float* __restrict__ out) {
    __shared__ float4 lds[8 * QB4];   // 53,376 B -> 3 blocks/CU
    const int tid = threadIdx.x;
    const long long b0 = (long long)blockIdx.x * 8;

    // ---- Stage A: coalesced load of x tile [8][32][48] into LDS (padded) ----
    const float4* xg = (const float4*)x + b0 * 384;   // 384 float4 per b-row
    #pragma unroll
    for (int it = 0; it < 12; ++it) {
        int v = tid + it * 256;          // 0..3071
        int b = v / 384;
        int w = v - b * 384;             // float4 idx within row
        int c = w / 12;
        int t4 = w - c * 12;
        lds[b * QB4 + c * QC4 + t4] = xg[v];
    }
    __syncthreads();

    // ---- Stage B: xh[b][c][:] = x[b][c][:] @ fwd  (in-place, thread = (b,c)) ----
    {
        const int b = tid >> 5, c = tid & 31;
        float4* row = &lds[b * QB4 + c * QC4];
        float xr[48];
        #pragma unroll
        for (int k = 0; k < 12; ++k) { float4 v = row[k]; LD4(xr, 4 * k, v); }
        float xh[48];
        for (int j = 0; j < 48; ++j) {
            const float* fr = fwdT + j * 48;   // uniform -> s_load, SGPR operand
            float acc = 0.0f;
            #pragma unroll
            for (int t = 0; t < 48; ++t) acc = fmaf(xr[t], fr[t], acc);
            xh[j] = acc;
        }
        #pragma unroll
        for (int k = 0; k < 12; ++k)
            row[k] = make_float4(xh[4 * k], xh[4 * k + 1], xh[4 * k + 2], xh[4 * k + 3]);
    }
    __syncthreads();

    // ---- Stage C: yh[j] = sum_{c,r} xh * kh   (thread = (b,f)) ----
    {
        const int b = tid & 7, f = tid >> 3;
        float yh[48];
        #pragma unroll
        for (int j = 0; j < 48; ++j) yh[j] = 0.0f;

        const float4* khp = (const float4*)kh + f * 384;   // kh[f][c][48]
        const float4* xrow0 = &lds[b * QB4];

        for (int c = 0; c < 32; ++c) {
            float xr[48], kr[48];
            const float4* xrow = xrow0 + c * QC4;
            #pragma unroll
            for (int k = 0; k < 12; ++k) { float4 v = xrow[k]; LD4(xr, 4 * k, v); }
            #pragma unroll
            for (int k = 0; k < 12; ++k) { float4 v = khp[c * 12 + k]; LD4(kr, 4 * k, v); }
            // d=1 irreps (j = 0..3): yh[n] += xr[n]*kr[n]
            #pragma unroll
            for (int n = 0; n < 4; ++n) yh[n] = fmaf(xr[n], kr[n], yh[n]);
            // d=2 irreps (j = 4 + 4n + 2p + q)
            #pragma unroll
            for (int n = 0; n < 2; ++n) {
                const int o = 4 + 4 * n;
                #pragma unroll
                for (int p = 0; p < 2; ++p) {
                    #pragma unroll
                    for (int q = 0; q < 2; ++q) {
                        float s = yh[o + 2 * p + q];
                        s = fmaf(xr[o + 2 * p + 0], kr[o + 0 + q], s);
                        s = fmaf(xr[o + 2 * p + 1], kr[o + 2 + q], s);
                        yh[o + 2 * p + q] = s;
                    }
                }
            }
            // d=3 irreps (j = 12 + 9n + 3p + q)
            #pragma unroll
            for (int n = 0; n < 4; ++n) {
                const int o = 12 + 9 * n;
                #pragma unroll
                for (int p = 0; p < 3; ++p) {
                    #pragma unroll
                    for (int q = 0; q < 3; ++q) {
                        float s = yh[o + 3 * p + q];
                        s = fmaf(xr[o + 3 * p + 0], kr[o + 0 + q], s);
                        s = fmaf(xr[o + 3 * p + 1], kr[o + 3 + q], s);
                        s = fmaf(xr[o + 3 * p + 2], kr[o + 6 + q], s);
                        yh[o + 3 * p + q] = s;
                    }
                }
            }
        }

        // ---- Stage D: y[s] = sum_j yh[j] * inv[j][s] + bias[f] ----
        float acc[48];
        const float bf = bias[f];
        #pragma unroll
        for (int s = 0; s < 48; ++s) acc[s] = bf;
        for (int j = 0; j < 48; ++j) {
            const float yj = yh[j];
            const float* ir = invm + j * 48;   // uniform -> s_load
            #pragma unroll
            for (int s = 0; s < 48; ++s) acc[s] = fmaf(yj, ir[s], acc[s]);
        }
        float4* op = (float4*)(out + ((b0 + b) * 32 + f) * 48);
        #pragma unroll
        for (int k = 0; k < 12; ++k)
            op[k] = make_float4(acc[4 * k], acc[4 * k + 1], acc[4 * k + 2], acc[4 * k + 3]);
    }
}

extern "C" void kernel_launch(void* const* d_in, const int* in_sizes, int n_in,
                              void* d_out, int out_size, void* d_ws, size_t ws_size,
                              hipStream_t stream) {
    const float* x    = (const float*)d_in[0];
    const float* kern = (const float*)d_in[1];
    const float* bias = (const float*)d_in[2];
    const float* d1   = (const float*)d_in[3];
    const float* d2   = (const float*)d_in[4];
    const float* d3   = (const float*)d_in[5];
    float* out = (float*)d_out;

    float* fwdT = (float*)d_ws;          // 2304 floats
    float* invm = fwdT + 2304;           // 2304 floats
    float* kh   = invm + 2304;           // 49152 floats   (total 215 KB of ws)

    prep_ft<<<9, 256, 0, stream>>>(d1, d2, d3, fwdT, invm);
    prep_kh<<<16, 256, 0, stream>>>(kern, fwdT, kh);
    fused_main<<<32768 / 8, 256, 0, stream>>>(x, fwdT, invm, kh, bias, out);
}

// Round 2
// 635.378 us; speedup vs baseline: 1.0607x; 1.0607x over previous
//
#include <hip/hip_runtime.h>

// DenseEquivariantIrrep: B=32768, C=32, F=32, NS=48, irreps: 4x(d=1), 2x(d=2), 4x(d=3)
// y[b,f,s] = sum_j (sum_{c,r} (x[b,c,:]@fwd)[n,p,r] * (kernel[f,c,:]@fwd)[n,r,q]) * inv[j,s] + bias[f]
//
// R2: register-pressure fix. R1 had VGPR=84 (compiler AGPR-spilled yh/xr/kr/acc),
// VALUBusy 49%, 467us. Changes: waves_per_eu(3,3) to unlock 168 VGPRs at the
// LDS-capped occupancy (3 blocks/CU); stage C split d1+d2 / d3 halves (peak live
// ~130); stage D loop-interchange over s-chunks of 4 against transposed invT
// (live ~60); stage B chunked j-writes (live ~60). Rolled outer loops for I$.

#define QB4 417   // float4 stride per b-row in LDS (b + 5c) mod 8 spreads bank quads
#define QC4 13    // float4 stride per c-row

// ---- prep 1: fwdT[j][t] = fwd[t][j];  invT[s][j] = fwd[s][j] * d_j/48 ----
__global__ void prep_ft(const float* __restrict__ d1, const float* __restrict__ d2,
                        const float* __restrict__ d3,
                        float* __restrict__ fwdT, float* __restrict__ invT) {
    int id = blockIdx.x * 256 + threadIdx.x;   // 0..2303
    if (id >= 48 * 48) return;
    int j = id / 48, t = id - j * 48;
    float v, scale;
    if (j < 4) {                       // d=1 irreps: [4][48][1][1]
        v = d1[j * 48 + t];
        scale = 1.0f / 48.0f;
    } else if (j < 12) {               // d=2 irreps: [2][48][2][2]
        int r = j - 4;
        int i = r >> 2, pq = r & 3;
        v = d2[i * 192 + t * 4 + pq];
        scale = 2.0f / 48.0f;
    } else {                           // d=3 irreps: [4][48][3][3]
        int r = j - 12;
        int i = r / 9, pq = r - i * 9;
        v = d3[i * 432 + t * 9 + pq];
        scale = 3.0f / 48.0f;
    }
    fwdT[j * 48 + t] = v;
    invT[t * 48 + j] = v * scale;      // transposed so stage D rows are contiguous
}

// ---- prep 2: kh[f][c][j] = sum_t kernel[f][c][t] * fwdT[j][t] ----
__global__ void prep_kh(const float* __restrict__ kern, const float* __restrict__ fwdT,
                        float* __restrict__ kh) {
    int id = blockIdx.x * 256 + threadIdx.x;   // 0..4095
    int f = id >> 7;
    int c = (id >> 2) & 31;
    int jq = id & 3;
    float kr[48];
    const float4* kp = (const float4*)(kern + (f * 32 + c) * 48);
    #pragma unroll
    for (int k = 0; k < 12; ++k) {
        float4 v = kp[k];
        kr[4*k] = v.x; kr[4*k+1] = v.y; kr[4*k+2] = v.z; kr[4*k+3] = v.w;
    }
    for (int jj = 0; jj < 12; ++jj) {
        int j = jq * 12 + jj;
        const float* fr = fwdT + j * 48;
        float acc = 0.0f;
        #pragma unroll
        for (int t = 0; t < 48; ++t) acc = fmaf(kr[t], fr[t], acc);
        kh[(f * 32 + c) * 48 + j] = acc;
    }
}

// ---- fused main: block = 8 b-rows x 32 f ----
__global__ __launch_bounds__(256) __attribute__((amdgpu_waves_per_eu(3, 3)))
void fused_main(
    const float* __restrict__ x,
    const float* __restrict__ fwdT,
    const float* __restrict__ invT,
    const float* __restrict__ kh,
    const float* __restrict__ bias,
    float* __restrict__ out) {
    __shared__ float4 lds[8 * QB4];   // 53,376 B -> 3 blocks/CU
    const int tid = threadIdx.x;
    const long long b0 = (long long)blockIdx.x * 8;

    // ---- Stage A: coalesced load of x tile [8][32][48] into LDS (padded) ----
    const float4* xg = (const float4*)x + b0 * 384;   // 384 float4 per b-row
    #pragma unroll
    for (int it = 0; it < 12; ++it) {
        int v = tid + it * 256;          // 0..3071
        int b = v / 384;
        int w = v - b * 384;             // float4 idx within row
        int c = w / 12;
        int t4 = w - c * 12;
        lds[b * QB4 + c * QC4 + t4] = xg[v];
    }
    __syncthreads();

    // ---- Stage B: xh[b][c][:] = x[b][c][:] @ fwd  (in-place, thread = (b,c)) ----
    {
        const int b = tid >> 5, c = tid & 31;
        float4* row = &lds[b * QB4 + c * QC4];
        float xr[48];
        #pragma unroll
        for (int k = 0; k < 12; ++k) {
            float4 v = row[k];
            xr[4*k] = v.x; xr[4*k+1] = v.y; xr[4*k+2] = v.z; xr[4*k+3] = v.w;
        }
        for (int jc = 0; jc < 12; ++jc) {      // rolled: live = xr[48] + h[4]
            float h[4];
            #pragma unroll
            for (int u = 0; u < 4; ++u) {
                const float* fr = fwdT + (jc * 4 + u) * 48;   // uniform -> s_load
                float acc = 0.0f;
                #pragma unroll
                for (int t = 0; t < 48; ++t) acc = fmaf(xr[t], fr[t], acc);
                h[u] = acc;
            }
            row[jc] = make_float4(h[0], h[1], h[2], h[3]);
        }
    }
    __syncthreads();

    // ---- Stage C: yh[j] = sum_{c,r} xh * kh   (thread = (b,f)) ----
    {
        const int b = tid & 7, f = tid >> 3;
        float yh[48];
        #pragma unroll
        for (int j = 0; j < 48; ++j) yh[j] = 0.0f;

        const float4* khp = (const float4*)kh + f * 384;   // kh[f][c][48]
        const float4* xrow0 = &lds[b * QB4];

        for (int c = 0; c < 32; ++c) {
            const float4* xrow = xrow0 + c * QC4;
            const float4* kp = khp + c * 12;

            // -- half 1: d1 + d2 irreps (floats 0..11) --
            {
                float xr[12], kr[12];
                #pragma unroll
                for (int k = 0; k < 3; ++k) {
                    float4 v = xrow[k];
                    xr[4*k] = v.x; xr[4*k+1] = v.y; xr[4*k+2] = v.z; xr[4*k+3] = v.w;
                    float4 w = kp[k];
                    kr[4*k] = w.x; kr[4*k+1] = w.y; kr[4*k+2] = w.z; kr[4*k+3] = w.w;
                }
                #pragma unroll
                for (int n = 0; n < 4; ++n) yh[n] = fmaf(xr[n], kr[n], yh[n]);
                #pragma unroll
                for (int n = 0; n < 2; ++n) {
                    const int o = 4 + 4 * n;
                    #pragma unroll
                    for (int p = 0; p < 2; ++p) {
                        #pragma unroll
                        for (int q = 0; q < 2; ++q) {
                            float s = yh[o + 2*p + q];
                            s = fmaf(xr[o + 2*p + 0], kr[o + 0 + q], s);
                            s = fmaf(xr[o + 2*p + 1], kr[o + 2 + q], s);
                            yh[o + 2*p + q] = s;
                        }
                    }
                }
            }
            // -- half 2: d3 irreps (floats 12..47) --
            {
                float xr[36], kr[36];
                #pragma unroll
                for (int k = 0; k < 9; ++k) {
                    float4 v = xrow[3 + k];
                    xr[4*k] = v.x; xr[4*k+1] = v.y; xr[4*k+2] = v.z; xr[4*k+3] = v.w;
                    float4 w = kp[3 + k];
                    kr[4*k] = w.x; kr[4*k+1] = w.y; kr[4*k+2] = w.z; kr[4*k+3] = w.w;
                }
                #pragma unroll
                for (int n = 0; n < 4; ++n) {
                    const int o = 9 * n;
                    #pragma unroll
                    for (int p = 0; p < 3; ++p) {
                        #pragma unroll
                        for (int q = 0; q < 3; ++q) {
                            float s = yh[12 + o + 3*p + q];
                            s = fmaf(xr[o + 3*p + 0], kr[o + 0 + q], s);
                            s = fmaf(xr[o + 3*p + 1], kr[o + 3 + q], s);
                            s = fmaf(xr[o + 3*p + 2], kr[o + 6 + q], s);
                            yh[12 + o + 3*p + q] = s;
                        }
                    }
                }
            }
        }

        // ---- Stage D: y[s] = sum_j yh[j] * invT[s][j] + bias[f] ----
        // loop-interchanged: 4 outputs at a time, live = yh[48] + a[4]
        const float bf = bias[f];
        float4* op = (float4*)(out + ((b0 + (long long)b) * 32 + f) * 48);
        for (int sc = 0; sc < 12; ++sc) {
            float a[4];
            #pragma unroll
            for (int u = 0; u < 4; ++u) {
                const float* ir = invT + (sc * 4 + u) * 48;   // uniform -> s_load
                float acc = bf;
                #pragma unroll
                for (int j = 0; j < 48; ++j) acc = fmaf(yh[j], ir[j], acc);
                a[u] = acc;
            }
            op[sc] = make_float4(a[0], a[1], a[2], a[3]);
        }
    }
}

extern "C" void kernel_launch(void* const* d_in, const int* in_sizes, int n_in,
                              void* d_out, int out_size, void* d_ws, size_t ws_size,
                              hipStream_t stream) {
    const float* x    = (const float*)d_in[0];
    const float* kern = (const float*)d_in[1];
    const float* bias = (const float*)d_in[2];
    const float* d1   = (const float*)d_in[3];
    const float* d2   = (const float*)d_in[4];
    const float* d3   = (const float*)d_in[5];
    float* out = (float*)d_out;

    float* fwdT = (float*)d_ws;          // 2304 floats
    float* invT = fwdT + 2304;           // 2304 floats
    float* kh   = invT + 2304;           // 49152 floats

    prep_ft<<<9, 256, 0, stream>>>(d1, d2, d3, fwdT, invT);
    prep_kh<<<16, 256, 0, stream>>>(kern, fwdT, kh);
    fused_main<<<32768 / 8, 256, 0, stream>>>(x, fwdT, invT, kh, bias, out);
}